// Round 9
// baseline (281.296 us; speedup 1.0000x reference)
//
#include <hip/hip_runtime.h>
#include <hip/hip_bf16.h>
#include <stdint.h>

#define USER_DIM 3706
#define ITEM_DIM 6040
#define LATENT   512
#define BATCH    8192
#define XCOLS    (USER_DIM + ITEM_DIM)   // 9746
#define KPAD_U   3744                     // 117 * 32  (117 % 3 == 0)
#define KPAD_I   6144                     // 2 halves x 96 steps (96 % 3 == 0)

typedef float f32x4 __attribute__((ext_vector_type(4)));
typedef short bf16x8 __attribute__((ext_vector_type(8)));

#define VMCNT(n) asm volatile("s_waitcnt vmcnt(" #n ")" ::: "memory")
#define LGKM0    asm volatile("s_waitcnt lgkmcnt(0)" ::: "memory")

static __device__ __forceinline__ unsigned short f2bf(float f) {
    union { float f; unsigned int u; } v; v.f = f;
    unsigned int u = v.u;
    u += 0x7fffu + ((u >> 16) & 1u);   // RNE (finite inputs)
    return (unsigned short)(u >> 16);
}
static __device__ __forceinline__ float bf2f(unsigned int b) {
    union { unsigned int u; float f; } v; v.u = b << 16; return v.f;
}
static __device__ __forceinline__ void gload16(const void* g, void* l) {
    __builtin_amdgcn_global_load_lds(
        (const __attribute__((address_space(1))) void*)g,
        (__attribute__((address_space(3))) void*)l, 16, 0, 0);
}
static __device__ __forceinline__ void BARRIER() {
    __builtin_amdgcn_sched_barrier(0);
    __builtin_amdgcn_s_barrier();
    __builtin_amdgcn_sched_barrier(0);
}

// ---- Kernel 1: weight fp32 -> bf16, zero-padded K ----
__global__ void convert_w(const float* __restrict__ W, unsigned short* __restrict__ Wb,
                          int K, int Kpad) {
    int c = blockIdx.x * blockDim.x + threadIdx.x;
    int r = blockIdx.y;
    if (c >= Kpad) return;
    unsigned short o = 0;
    if (c < K) o = f2bf(W[(size_t)r * K + c]);
    Wb[(size_t)r * Kpad + c] = o;
}

// ---- Kernel 2: fused towers. 128x128 tile, BK=32, 4 waves.  Round-6 body
// with a DEEP pipeline: A reg-staged 3 tiles ahead (3 named sets, 3-unroll),
// B via global_load_lds into a 4-slot LDS ring issued 3 tiles ahead.
// Steady state: 12 vm-ops/lane in flight, vmcnt(12) mid-loop (never 0).
// LDS layout (A,B identical, 0-conflict): [64 segs][128B]; (row r, chunk g)
// at seg=r>>1, c8=((r&1)*4+g)^(seg&7). Linear writes, swizzle on source/read.
__global__ __launch_bounds__(256, 3) void gemm_fused(
    const float* __restrict__ X,
    const unsigned short* __restrict__ WuB, const float* __restrict__ bu,
    const unsigned short* __restrict__ WiB,
    unsigned short* __restrict__ Uemb,
    unsigned short* __restrict__ P0, unsigned short* __restrict__ P1)
{
    __shared__ unsigned short sA2[2][64 * 64];   // 2 x 8 KB bf16
    __shared__ unsigned short sB4[4][64 * 64];   // 4 x 8 KB bf16 (ring)

    const int tid  = threadIdx.x;
    const int lane = tid & 63;
    const int wid  = tid >> 6;
    const int wm   = wid >> 1;
    const int wn   = wid & 1;

    // XCD-chunked bijective swizzle over 768 blocks (= 8 * 96).
    const int bid = blockIdx.x;
    const int swz = (bid & 7) * 96 + (bid >> 3);
    const int g4  = swz >> 2;          // 0..191
    const int nb  = swz & 3;

    // balanced tower interleave: per CU 1 user (117 steps) + 2 item halves (96)
    int mb, k0s, nt, xoff, Kpad;
    const unsigned short* WB;
    bool isUser; int kh = 0;
    if (g4 % 3 == 0) {
        isUser = true;  mb = g4 / 3;
        k0s = 0; nt = KPAD_U / 32; xoff = 0; Kpad = KPAD_U; WB = WuB;
    } else {
        const int q = g4 - (g4 / 3 + 1);     // 0..127 bijective
        isUser = false; mb = q >> 1; kh = q & 1;
        k0s = kh * 96; nt = 96; xoff = USER_DIM; Kpad = KPAD_I; WB = WiB;
    }

    // ---- staging lane geometry (LDS[seg][c8] holds global
    //      (row = seg*2 + ((c8^(seg&7))>>2), kchunk = (c8^(seg&7))&3)) ----
    const int l8  = lane >> 3;                 // seg within group
    const int c8w = lane & 7;                  // LDS chunk this lane fills
    const int s8  = c8w ^ l8;                  // source-side swizzled chunk
    const int spr = s8 >> 2;                   // source row parity
    const int skc = (s8 & 3) * 8;              // source k-col (elements)

    // A: 128 rows x 32 k; thread covers 2 segs (rows sego*2+spr), 8 f32 each
    const int asg0 = wid * 16 + l8;            // op0 seg (0..63 across waves)
    const float* aptr0 = X + (size_t)(mb * 128 + asg0 * 2 + spr) * XCOLS + xoff;
    const float* aptr1 = aptr0 + (size_t)16 * XCOLS;   // op1 seg = asg0 + 8

    auto ALOAD = [&](f32x4 (&R)[4], int tk) {
        int kc = tk * 32 + skc;
        if (xoff + kc + 8 > XCOLS) kc = XCOLS - xoff - 8;  // item tail: junk x 0-B
        R[0] = *(const f32x4*)(aptr0 + kc);
        R[1] = *(const f32x4*)(aptr0 + kc + 4);
        R[2] = *(const f32x4*)(aptr1 + kc);
        R[3] = *(const f32x4*)(aptr1 + kc + 4);
    };
    auto AWRITE = [&](const f32x4 (&R)[4], int buf) {
        unsigned short* sA = sA2[buf];
        uint4 w0, w1;
        w0.x = (unsigned)f2bf(R[0].x) | ((unsigned)f2bf(R[0].y) << 16);
        w0.y = (unsigned)f2bf(R[0].z) | ((unsigned)f2bf(R[0].w) << 16);
        w0.z = (unsigned)f2bf(R[1].x) | ((unsigned)f2bf(R[1].y) << 16);
        w0.w = (unsigned)f2bf(R[1].z) | ((unsigned)f2bf(R[1].w) << 16);
        w1.x = (unsigned)f2bf(R[2].x) | ((unsigned)f2bf(R[2].y) << 16);
        w1.y = (unsigned)f2bf(R[2].z) | ((unsigned)f2bf(R[2].w) << 16);
        w1.z = (unsigned)f2bf(R[3].x) | ((unsigned)f2bf(R[3].y) << 16);
        w1.w = (unsigned)f2bf(R[3].z) | ((unsigned)f2bf(R[3].w) << 16);
        *(uint4*)(sA + asg0 * 64 + c8w * 8) = w0;
        *(uint4*)(sA + (asg0 + 8) * 64 + c8w * 8) = w1;
    };
    auto ISSUE_B = [&](int tk, int slot) {
        const int kb = tk * 32;
        unsigned short* sB = sB4[slot];
        #pragma unroll
        for (int j = 0; j < 2; ++j) {
            const int i  = wid * 2 + j;                // 0..7
            const int rt = (i * 8 + l8) * 2 + spr;     // tile row
            const unsigned short* s =
                WB + (size_t)(nb * 128 + rt) * Kpad + kb + skc;
            gload16(s, sB + i * 512);                  // linear 1KB dest
        }
    };

    // ---- fragment read geometry (0-conflict, as r6) ----
    const int fr  = lane & 15;
    const int g   = lane >> 4;
    const int lro = (fr >> 1) * 64 + ((((fr & 1) * 4) + g) ^ (fr >> 1)) * 8;
    const int aro = wm * 2048 + lro;           // + mi*512
    const int bro = wn * 2048 + lro;           // + ni*512

    f32x4 acc[4][4];
    #pragma unroll
    for (int i = 0; i < 4; ++i)
        #pragma unroll
        for (int j = 0; j < 4; ++j) acc[i][j] = (f32x4)0.0f;

    auto COMPUTE = [&](int abuf, int slot) {
        const unsigned short* sA = sA2[abuf];
        const unsigned short* sB = sB4[slot];
        bf16x8 af[4], bfr[4];
        #pragma unroll
        for (int mi = 0; mi < 4; ++mi)
            af[mi] = *(const bf16x8*)(sA + aro + mi * 512);
        #pragma unroll
        for (int ni = 0; ni < 4; ++ni)
            bfr[ni] = *(const bf16x8*)(sB + bro + ni * 512);
        __builtin_amdgcn_s_setprio(1);
        #pragma unroll
        for (int mi = 0; mi < 4; ++mi)
            #pragma unroll
            for (int ni = 0; ni < 4; ++ni)
                acc[mi][ni] = __builtin_amdgcn_mfma_f32_16x16x32_bf16(
                    af[mi], bfr[ni], acc[mi][ni], 0, 0, 0);
        __builtin_amdgcn_s_setprio(0);
    };

    f32x4 rs0[4], rs1[4], rs2[4];     // A(k) lives in set k%3 (named, static)

    // ---- prologue: 3 tiles of A and B in flight ----
    ALOAD(rs0, k0s + 0); ISSUE_B(k0s + 0, 0);     // 4 + 2
    ALOAD(rs1, k0s + 1); ISSUE_B(k0s + 1, 1);     // 4 + 2
    ALOAD(rs2, k0s + 2); ISSUE_B(k0s + 2, 2);     // 4 + 2  -> 18
    AWRITE(rs0, 0);                  // auto-waits A(0) (vmcnt(14))
    LGKM0;
    VMCNT(12);                       // B(0) landed; rest in flight
    BARRIER();                       // tile 0 ready

    // ---- main loop: 3-unrolled, one AWRITE+ALOAD+ISSUE per step,
    //      vmcnt(12) mid-loop (retires only B(t+1)) ----
    #define GSTEP(T, SW, SL)                                   \
    {                                                          \
        const int t_ = (T);                                    \
        COMPUTE(t_ & 1, t_ & 3);                               \
        AWRITE(SW, (t_ + 1) & 1);   /* auto vmcnt: A(t+1) */   \
        ALOAD(SL, k0s + t_ + 3);                               \
        LGKM0;                                                 \
        BARRIER();                                             \
        ISSUE_B(k0s + t_ + 3, (t_ + 3) & 3);                   \
        VMCNT(12);                                             \
        BARRIER();                                             \
    }

    for (int T = 0; T + 5 < nt; T += 3) {
        GSTEP(T,     rs1, rs0)
        GSTEP(T + 1, rs2, rs1)
        GSTEP(T + 2, rs0, rs2)
    }
    #undef GSTEP

    // ---- epilogue: steps nt-3, nt-2, nt-1 (nt % 3 == 0) ----
    {
        const int t0 = nt - 3;
        COMPUTE(t0 & 1, t0 & 3);
        AWRITE(rs1, (t0 + 1) & 1);   // A(nt-2): set (nt-2)%3 == 1
        LGKM0;
        BARRIER();
        VMCNT(6);                    // B(nt-2) landed
        BARRIER();

        const int t1 = nt - 2;
        COMPUTE(t1 & 1, t1 & 3);
        AWRITE(rs2, (t1 + 1) & 1);   // A(nt-1): set (nt-1)%3 == 2
        LGKM0;
        BARRIER();
        VMCNT(0);                    // drain B(nt-1)
        BARRIER();

        const int t2 = nt - 1;
        COMPUTE(t2 & 1, t2 & 3);
    }

    // ---- epilogue stores ----
    const int cb = nb * 128 + wn * 64;
    const int rb = mb * 128 + wm * 64 + (lane >> 4) * 4;
    if (isUser) {
        #pragma unroll
        for (int ni = 0; ni < 4; ++ni) {
            const int col = cb + ni * 16 + fr;
            const float bv = bu[col];
            #pragma unroll
            for (int mi = 0; mi < 4; ++mi) {
                f32x4 v = acc[mi][ni];
                #pragma unroll
                for (int r = 0; r < 4; ++r) {
                    const int row = rb + mi * 16 + r;
                    Uemb[(size_t)row * LATENT + col] = f2bf(fmaxf(v[r] + bv, 0.0f));
                }
            }
        }
    } else {
        unsigned short* P = kh ? P1 : P0;
        #pragma unroll
        for (int ni = 0; ni < 4; ++ni) {
            const int col = cb + ni * 16 + fr;
            #pragma unroll
            for (int mi = 0; mi < 4; ++mi) {
                f32x4 v = acc[mi][ni];
                #pragma unroll
                for (int r = 0; r < 4; ++r) {
                    const int row = rb + mi * 16 + r;
                    P[(size_t)row * LATENT + col] = f2bf(v[r]);   // partial
                }
            }
        }
    }
}

// ---- Kernel 3: out[b] = sum_d U[b,d] * relu(P0[b,d] + P1[b,d] + bi[d]) ----
__global__ void rowdot(const unsigned short* __restrict__ U,
                       const unsigned short* __restrict__ P0,
                       const unsigned short* __restrict__ P1,
                       const float* __restrict__ bi,
                       float* __restrict__ out) {
    const int lane = threadIdx.x & 63;
    const int w    = threadIdx.x >> 6;
    const int row  = blockIdx.x * 4 + w;
    const size_t base = (size_t)row * LATENT + lane * 8;
    const uint4 uv = *(const uint4*)(U  + base);
    const uint4 p0 = *(const uint4*)(P0 + base);
    const uint4 p1 = *(const uint4*)(P1 + base);
    const float4 b0 = *(const float4*)(bi + lane * 8);
    const float4 b1 = *(const float4*)(bi + lane * 8 + 4);
    const float bb[8] = {b0.x, b0.y, b0.z, b0.w, b1.x, b1.y, b1.z, b1.w};
    const unsigned int* up = (const unsigned int*)&uv;
    const unsigned int* q0 = (const unsigned int*)&p0;
    const unsigned int* q1 = (const unsigned int*)&p1;
    float acc = 0.0f;
    #pragma unroll
    for (int q = 0; q < 4; ++q) {
        float ilo = fmaxf(bf2f(q0[q] & 0xffffu) + bf2f(q1[q] & 0xffffu) + bb[2 * q], 0.0f);
        float ihi = fmaxf(bf2f(q0[q] >> 16)     + bf2f(q1[q] >> 16)     + bb[2 * q + 1], 0.0f);
        acc += bf2f(up[q] & 0xffffu) * ilo;
        acc += bf2f(up[q] >> 16)     * ihi;
    }
    #pragma unroll
    for (int off = 32; off >= 1; off >>= 1)
        acc += __shfl_xor(acc, off, 64);
    if (lane == 0) out[row] = acc;
}

extern "C" void kernel_launch(void* const* d_in, const int* in_sizes, int n_in,
                              void* d_out, int out_size, void* d_ws, size_t ws_size,
                              hipStream_t stream) {
    const float* x  = (const float*)d_in[0];
    const float* Wu = (const float*)d_in[1];
    const float* bu = (const float*)d_in[2];
    const float* Wi = (const float*)d_in[3];
    const float* bi = (const float*)d_in[4];
    float* out = (float*)d_out;

    unsigned short* WuB  = (unsigned short*)d_ws;                 // 512*3744 bf16
    unsigned short* WiB  = WuB + (size_t)LATENT * KPAD_U;         // 512*6144 bf16
    unsigned short* Uemb = WiB + (size_t)LATENT * KPAD_I;         // 8192*512 bf16
    unsigned short* P0   = Uemb + (size_t)BATCH * LATENT;         // 8192*512 bf16
    unsigned short* P1   = P0   + (size_t)BATCH * LATENT;         // 8192*512 bf16

    convert_w<<<dim3((KPAD_U + 255) / 256, LATENT), 256, 0, stream>>>(Wu, WuB, USER_DIM, KPAD_U);
    convert_w<<<dim3((KPAD_I + 255) / 256, LATENT), 256, 0, stream>>>(Wi, WiB, ITEM_DIM, KPAD_I);

    // 768 blocks = 3 per CU co-resident; 1 user + 2 item halves per CU.
    gemm_fused<<<768, 256, 0, stream>>>(x, WuB, bu, WiB, Uemb, P0, P1);

    rowdot<<<BATCH / 4, 256, 0, stream>>>(Uemb, P0, P1, bi, out);
}